// Round 3
// baseline (204.974 us; speedup 1.0000x reference)
//
#include <hip/hip_runtime.h>

// Batched Kalman step: G groups, S=16, M=8, fp32. One wave per group,
// 4 waves/block, wave-private LDS (no __syncthreads; same-wave DS is in-order).
//
// R3: inputs (cov/F/H/R/mean/in/Q) are read straight from global (L1/L2-hot),
// LDS holds only computed intermediates. GJ solve: pivot via v_readlane +
// v_rcp_f32, 4 bpermutes/iter. new_mean via shfl-xor reduction.
// LDS/wave = 3264 B -> 13056 B/block -> 12-block LDS cap; VGPR<=64 for 32 waves/CU.

#define WSYNC() asm volatile("" ::: "memory")

__device__ __forceinline__ float lane_bcast(float v, int srclane) {
    return __int_as_float(__builtin_amdgcn_readlane(__float_as_int(v), srclane));
}
__device__ __forceinline__ float dot4(float4 a, float4 b) {
    return a.x*b.x + a.y*b.y + a.z*b.z + a.w*b.w;
}

__global__ __launch_bounds__(256, 8) void kalman_kernel(
    const float* __restrict__ g_in,
    const float* __restrict__ g_mean,
    const float* __restrict__ g_cov,
    const float* __restrict__ g_H,
    const float* __restrict__ g_R,
    const float* __restrict__ g_F,
    const float* __restrict__ g_Q,
    float* __restrict__ g_out,
    int G)
{
    // per-wave LDS (floats): CT[8][20]@0, CTT[16][12]@160, X[8][16]@352,
    // NC[16][20]@480, NM[16]@800; T3[16][20]@0 overlaps CT/CTT (dead by then).
    __shared__ __align__(16) float smem[4][816];
    const int wv   = threadIdx.x >> 6;
    const int lane = threadIdx.x & 63;
    const int g    = (blockIdx.x << 2) | wv;
    float* const sm   = smem[wv];
    float* const sCT  = sm;
    float* const sCTT = sm + 160;
    float* const sX   = sm + 352;
    float* const sNC  = sm + 480;
    float* const sNM  = sm + 800;
    float* const sT3  = sm;

    const int r  = lane >> 2;        // 0..15
    const int c0 = (lane & 3) << 2;  // 0,4,8,12
    const int gi = lane >> 3;        // 0..7
    const int gj = lane & 7;         // 0..7

    const float* const Gcov = g_cov + (size_t)g * 256;
    const float* const GF   = g_F   + (size_t)g * 256;
    const float* const GQ   = g_Q   + (size_t)g * 256;
    const float* const GH   = g_H   + (size_t)g * 128;
    const float* const GR   = g_R   + (size_t)g * 64;
    const float* const Gm   = g_mean + (size_t)g * 16;

    // ---- H row gi into registers (reused for CT, Ssys, resid) ----
    float4 hq[4];
    #pragma unroll
    for (int q = 0; q < 4; ++q)
        hq[q] = *reinterpret_cast<const float4*>(GH + gi*16 + 4*q);

    // ---- 1: CT = H@cov (cov symmetric): lane (gi,gj) does CT[gi][2gj],[2gj+1] ----
    {
        float a0 = 0.f, a1 = 0.f;
        #pragma unroll
        for (int q = 0; q < 4; ++q) {
            const float4 ca = *reinterpret_cast<const float4*>(Gcov + (2*gj  )*16 + 4*q);
            const float4 cb = *reinterpret_cast<const float4*>(Gcov + (2*gj+1)*16 + 4*q);
            a0 += dot4(hq[q], ca);
            a1 += dot4(hq[q], cb);
        }
        *reinterpret_cast<float2*>(sCT + gi*20 + 2*gj) = make_float2(a0, a1);
        sCTT[(2*gj  )*12 + gi] = a0;      // CT^T for the NC step
        sCTT[(2*gj+1)*12 + gi] = a1;
    }
    WSYNC();

    // ---- 2: a = Ssys[gi][gj]; b0,b1 = CT[gi][gj], CT[gi][gj+8]; resid ----
    float a = GR[gi*8 + gj];
    #pragma unroll
    for (int q = 0; q < 4; ++q) {
        const float4 ct = *reinterpret_cast<const float4*>(sCT + gj*20 + 4*q);
        a += dot4(hq[q], ct);
    }
    float b0 = sCT[gi*20 + gj];
    float b1 = sCT[gi*20 + gj + 8];
    float rin = g_in[(size_t)g*8 + gi];
    #pragma unroll
    for (int q = 0; q < 4; ++q) {
        const float4 m4 = *reinterpret_cast<const float4*>(Gm + 4*q);
        rin -= dot4(hq[q], m4);
    }

    // ---- 3: in-register Gauss-Jordan: [Ssys | CT] -> X = Ssys^-1 CT ----
    #pragma unroll
    for (int k = 0; k < 8; ++k) {
        const float p    = lane_bcast(a, 9*k);                 // pivot via readlane (SGPR)
        const float pinv = __builtin_amdgcn_rcpf(p);           // v_rcp_f32 (~1e-7 rel, fine)
        const float akj  = __shfl(a,  (k << 3) | gj);
        const float bkj0 = __shfl(b0, (k << 3) | gj);
        const float bkj1 = __shfl(b1, (k << 3) | gj);
        const float aik  = __shfl(a,  (gi << 3) | k);
        const float ra  = akj*pinv, rb0 = bkj0*pinv, rb1 = bkj1*pinv;
        const bool diag = (gi == k);
        a  = diag ? ra  : a  - aik*ra;
        b0 = diag ? rb0 : b0 - aik*rb0;
        b1 = diag ? rb1 : b1 - aik*rb1;
    }
    sX[gi*16 + gj]     = b0;
    sX[gi*16 + gj + 8] = b1;

    // ---- 4: new_mean[s] = mean[s] + sum_m X[m][s]*resid[m]  (shfl-xor reduce) ----
    {
        float p0 = b0 * rin, p1 = b1 * rin;
        p0 += __shfl_xor(p0, 8);  p1 += __shfl_xor(p1, 8);
        p0 += __shfl_xor(p0, 16); p1 += __shfl_xor(p1, 16);
        p0 += __shfl_xor(p0, 32); p1 += __shfl_xor(p1, 32);
        if (gi == 0) {
            sNM[gj]     = Gm[gj]     + p0;
            sNM[gj + 8] = Gm[gj + 8] + p1;
        }
    }
    WSYNC();

    // ---- 5: NC = cov - CT^T @ X  (lane (r,c0) -> NC[r][c0..3]) ----
    {
        float4 n = *reinterpret_cast<const float4*>(Gcov + lane*4);  // cov[r][c0..3]
        const float4 cta = *reinterpret_cast<const float4*>(sCTT + r*12);
        const float4 ctb = *reinterpret_cast<const float4*>(sCTT + r*12 + 4);
        const float ctt[8] = {cta.x,cta.y,cta.z,cta.w, ctb.x,ctb.y,ctb.z,ctb.w};
        #pragma unroll
        for (int m = 0; m < 8; ++m) {
            const float4 xq = *reinterpret_cast<const float4*>(sX + m*16 + c0);
            n.x -= ctt[m]*xq.x; n.y -= ctt[m]*xq.y; n.z -= ctt[m]*xq.z; n.w -= ctt[m]*xq.w;
        }
        *reinterpret_cast<float4*>(sNC + r*20 + c0) = n;
    }
    WSYNC();

    // ---- F row r into registers (pred_mean, T3, pred_cov all use it) ----
    float4 fq[4];
    #pragma unroll
    for (int q = 0; q < 4; ++q)
        fq[q] = *reinterpret_cast<const float4*>(GF + r*16 + 4*q);

    // ---- 6: pred_mean[r] = dot(F row r, nm) (4x redundant, masked store) ----
    {
        float pm = 0.f;
        #pragma unroll
        for (int q = 0; q < 4; ++q) {
            const float4 nm = *reinterpret_cast<const float4*>(sNM + 4*q);
            pm += dot4(fq[q], nm);
        }
        if ((lane & 3) == 0) g_out[(size_t)g*16 + r] = pm;
    }

    // ---- 7: T3 = F@NC (NC symmetric): T3[r][c0..3] = dot(F row r, NC rows c0+x) ----
    {
        float t[4];
        #pragma unroll
        for (int x = 0; x < 4; ++x) {
            float acc = 0.f;
            #pragma unroll
            for (int q = 0; q < 4; ++q) {
                const float4 nc = *reinterpret_cast<const float4*>(sNC + (c0+x)*20 + 4*q);
                acc += dot4(fq[q], nc);
            }
            t[x] = acc;
        }
        *reinterpret_cast<float4*>(sT3 + r*20 + c0) = make_float4(t[0],t[1],t[2],t[3]);
    }
    WSYNC();

    // ---- 8: pred_cov (transposed): out[c0+x][r] = dot(T3 row c0+x, F row r) + Q[c0+x][r]
    //         Q symmetric -> Q[c0+x][r] = Q[r][c0+x] = lane's natural quad. ----
    {
        const float4 qv = *reinterpret_cast<const float4*>(GQ + lane*4);
        const float qq[4] = {qv.x, qv.y, qv.z, qv.w};
        float* const g_pc = g_out + (size_t)G*16 + (size_t)g*256;
        #pragma unroll
        for (int x = 0; x < 4; ++x) {
            float acc = qq[x];
            #pragma unroll
            for (int q = 0; q < 4; ++q) {
                const float4 t3 = *reinterpret_cast<const float4*>(sT3 + (c0+x)*20 + 4*q);
                acc += dot4(fq[q], t3);
            }
            g_pc[(c0+x)*16 + r] = acc;
        }
    }
}

extern "C" void kernel_launch(void* const* d_in, const int* in_sizes, int n_in,
                              void* d_out, int out_size, void* d_ws, size_t ws_size,
                              hipStream_t stream) {
    const float* g_in   = (const float*)d_in[0];
    const float* g_mean = (const float*)d_in[1];
    const float* g_cov  = (const float*)d_in[2];
    const float* g_H    = (const float*)d_in[3];
    const float* g_R    = (const float*)d_in[4];
    const float* g_F    = (const float*)d_in[5];
    const float* g_Q    = (const float*)d_in[6];
    float* out = (float*)d_out;
    const int G = in_sizes[2] / 256;   // cov is [G,16,16]
    kalman_kernel<<<G/4, 256, 0, stream>>>(g_in, g_mean, g_cov, g_H, g_R, g_F, g_Q, out, G);
}